// Round 6
// baseline (754.145 us; speedup 1.0000x reference)
//
#include <hip/hip_runtime.h>

#define TSEQ 512

typedef _Float16 half8 __attribute__((ext_vector_type(8)));
typedef __attribute__((ext_vector_type(4))) float f32x4;

#define MFMAH(a,b,c) __builtin_amdgcn_mfma_f32_16x16x32_f16(a,b,c,0,0,0)

static __device__ __forceinline__ float sigm(float x){ return __builtin_amdgcn_rcpf(1.0f + __expf(-x)); }
static __device__ __forceinline__ float tanh_f(float x){ return 1.0f - 2.0f*__builtin_amdgcn_rcpf(__expf(2.0f*x)+1.0f); }

static __device__ __forceinline__ short f2h(float v){
  union { _Float16 h; short s; } u; u.h = (_Float16)v; return u.s;
}

// wait lgkmcnt(0) only (vmcnt left alone so x-prefetch stays in flight)
static __device__ __forceinline__ void lds_drain(){
  __builtin_amdgcn_s_waitcnt(0xC07F);
  __asm__ __volatile__("" ::: "memory");
}

// raw workgroup barrier WITHOUT the implicit vmcnt(0) drain of __syncthreads
static __device__ __forceinline__ void bar(){
  __asm__ __volatile__("" ::: "memory");
  __builtin_amdgcn_s_barrier();
  __asm__ __volatile__("" ::: "memory");
}

// TWO-RESIDENT-CHAIN LSTM. Lesson of R0-R5: occupancy was GRID-limited
// (grid 256 = 1 WG/CU); the register cliff only exists for 512-thr WGs
// (weights = 32 VGPR/thread floor). This version: 4-wave WGs (256 thr)
// where EVERY wave runs BOTH layers (weights for both layers in VGPR:
// 128 regs) -> total ~190 <= 256 -> 2 waves/SIMD -> TWO co-resident
// 4-wave WGs per CU = two INDEPENDENT recurrence chains interleaving,
// filling the ~60% latency stalls R0 exposed. Grid 512, 2 rows/WG.
// Structure per step (2 raw barriers):
//   phase1: gates0(i) = x(i)·Wih0 + h0(i-1)·Whh0 -> roundtrip -> cell ->
//           h0(i) -> bar
//   phase2: gates1(i) = h0(i)·Wih1 + h1(i-1)·Whh1 -> roundtrip -> cell ->
//           h1(i), stage x(i+1), prefetch x(i+2) -> bar
// All index algebra (si frag-order staging, foff A-frag reads, in-wave
// gbuf roundtrip, cell mapping) is R0's proven code, verbatim.
// gbuf columns are wave-private (jc = p*16+lr) -> the two phases can
// share one gbuf with no cross-wave hazard; barriers only protect act.
// Rows 2-3 of the 16-row MFMA tile are garbage (clamped-x duplicates,
// row-isolated in the matmul, bounded by sigmoid/tanh); never stored.
// act arrs: 0,1 x buf0/1; 2,3 h0 buf0/1; 4,5 h1 buf0/1 (frag-ordered).
extern "C" __global__ void __launch_bounds__(256, 2)
lstm_2wg(const float* __restrict__ x,
         const float* __restrict__ wih0, const float* __restrict__ whh0,
         const float* __restrict__ bih0, const float* __restrict__ bhh0,
         const float* __restrict__ wih1, const float* __restrict__ whh1,
         const float* __restrict__ bih1, const float* __restrict__ bhh1,
         const float* __restrict__ fcw,  const float* __restrict__ fcb,
         float* __restrict__ out)
{
  __shared__ __align__(16) short act[6][256];
  __shared__ __align__(16) float gbuf[1024];     // [q*256 + jc*4 + m], wave-private cols
  __shared__ float fcpart[16];

  const int tid = threadIdx.x;                   // 0..255 (4 waves)
  const int p   = tid >> 6;                      // wave: col-quarter
  const int ln  = tid & 63;
  const int lq  = ln >> 4;
  const int lr  = ln & 15;
  const int b0  = blockIdx.x << 1;               // 2 batch rows per WG
  const int jc  = (p << 4) + lr;                 // unit / gemm col (0..63)
  const int si  = (((jc>>5)*4 + ((jc>>3)&3))*4 + lq)*8 + (jc&7);  // frag-order slot
  const int foff = lq*32 + lr*8;                 // A-frag read offset (shorts)
  const bool wlane = (lq == 0);

  // ---- one-time: fp16 weight B-frags for BOTH layers: W[L][op][F][q] = 128 VGPR ----
  half8 W[2][2][2][4];
  {
    const float* wsrc[2][2] = { { wih0, whh0 }, { wih1, whh1 } };
#pragma unroll
    for (int L = 0; L < 2; ++L)
#pragma unroll
      for (int op = 0; op < 2; ++op)
#pragma unroll
        for (int F = 0; F < 2; ++F)
#pragma unroll
          for (int q = 0; q < 4; ++q){
            const float* src = wsrc[L][op] + ((q<<6) + jc)*64 + F*32 + lq*8;
#pragma unroll
            for (int e = 0; e < 8; ++e)
              W[L][op][F][q][e] = (_Float16)src[e];
          }
  }
  // bias as scalars, applied post-roundtrip (R3-proven): bq[L][q] for col jc
  float bq[2][4];
  {
#pragma unroll
    for (int L = 0; L < 2; ++L){
      const float* bi = L ? bih1 : bih0;
      const float* bh = L ? bhh1 : bhh0;
#pragma unroll
      for (int q = 0; q < 4; ++q)
        bq[L][q] = bi[(q<<6)+jc] + bh[(q<<6)+jc];
    }
  }
  const f32x4 Zq = {0.f, 0.f, 0.f, 0.f};

  // x source: rows 2-3 of the tile are garbage, clamp to row 0 (finite)
  const int xrow = (lq < 2) ? lq : 0;
  const float* xq = x + (size_t)(b0 + xrow)*(TSEQ*64) + jc;

  float c0st = 0.f, c1st = 0.f, h1v = 0.f, xv = 0.f;

  // ---- prologue: zero h bufs (act[2..5]), stage x(0), prefetch x(1) ----
  {
    int* hz = (int*)&act[2][0];
    for (int idx = tid; idx < 4*128; idx += 256) hz[idx] = 0;
  }
  act[0][si] = f2h(xq[0]);     // x(0) -> x buf0
  xv = xq[64];                 // x(1)
  __syncthreads();

  for (int i = 0; i < TSEQ; ++i){
    const int cb = i & 1, nb = cb ^ 1;

    // ---------- phase 1: layer0 ----------
    {
      const short* xb  = &act[0+cb][0];          // x(i)
      const short* h0b = &act[2+nb][0];          // h0(i-1)
      half8 a0 = *(const half8*)(xb  + foff);
      half8 b0v = *(const half8*)(h0b + foff);
      half8 a1 = *(const half8*)(xb  + foff + 128);
      half8 b1v = *(const half8*)(h0b + foff + 128);
      f32x4 acc[4];
#pragma unroll
      for (int q = 0; q < 4; ++q){
        acc[q] = MFMAH(a0,  W[0][0][0][q], Zq);
        acc[q] = MFMAH(b0v, W[0][1][0][q], acc[q]);
        acc[q] = MFMAH(a1,  W[0][0][1][q], acc[q]);
        acc[q] = MFMAH(b1v, W[0][1][1][q], acc[q]);
      }
      if (wlane){
#pragma unroll
        for (int q = 0; q < 4; ++q) *(f32x4*)&gbuf[q*256 + jc*4] = acc[q];
      }
      lds_drain();
      float gi = sigm  (gbuf[0*256 + jc*4 + lq] + bq[0][0]);
      float gf = sigm  (gbuf[1*256 + jc*4 + lq] + bq[0][1]);
      float gg = tanh_f(gbuf[2*256 + jc*4 + lq] + bq[0][2]);
      float go = sigm  (gbuf[3*256 + jc*4 + lq] + bq[0][3]);
      c0st = gf*c0st + gi*gg;
      float h = go * tanh_f(c0st);
      act[2+cb][si] = f2h(h);                    // h0(i)
      lds_drain();
      bar();
    }

    // ---------- phase 2: layer1 ----------
    {
      const short* h0b = &act[2+cb][0];          // h0(i)
      const short* h1b = &act[4+nb][0];          // h1(i-1)
      half8 a0 = *(const half8*)(h0b + foff);
      half8 b0v = *(const half8*)(h1b + foff);
      half8 a1 = *(const half8*)(h0b + foff + 128);
      half8 b1v = *(const half8*)(h1b + foff + 128);
      f32x4 acc[4];
#pragma unroll
      for (int q = 0; q < 4; ++q){
        acc[q] = MFMAH(a0,  W[1][0][0][q], Zq);
        acc[q] = MFMAH(b0v, W[1][1][0][q], acc[q]);
        acc[q] = MFMAH(a1,  W[1][0][1][q], acc[q]);
        acc[q] = MFMAH(b1v, W[1][1][1][q], acc[q]);
      }
      if (wlane){
#pragma unroll
        for (int q = 0; q < 4; ++q) *(f32x4*)&gbuf[q*256 + jc*4] = acc[q];
      }
      lds_drain();
      float gi = sigm  (gbuf[0*256 + jc*4 + lq] + bq[1][0]);
      float gf = sigm  (gbuf[1*256 + jc*4 + lq] + bq[1][1]);
      float gg = tanh_f(gbuf[2*256 + jc*4 + lq] + bq[1][2]);
      float go = sigm  (gbuf[3*256 + jc*4 + lq] + bq[1][3]);
      c1st = gf*c1st + gi*gg;
      h1v  = go * tanh_f(c1st);
      act[4+cb][si] = f2h(h1v);                  // h1(i)
      if (i < TSEQ-1){
        act[0+nb][si] = f2h(xv);                 // stage x(i+1)
        int tn = i + 2; if (tn > TSEQ-1) tn = TSEQ-1;
        xv = xq[tn << 6];                        // prefetch x(i+2)
      }
      lds_drain();
      bar();
    }
  }

  // ---- FC head: thread holds h1(T-1) for (unit jc, row lq) ----
  {
    float v = h1v * fcw[jc];
    v += __shfl_xor(v, 1); v += __shfl_xor(v, 2);
    v += __shfl_xor(v, 4); v += __shfl_xor(v, 8);
    if (lr == 0) fcpart[p*4 + lq] = v;
  }
  __syncthreads();
  if (tid < 2)
    out[b0 + tid] = fcpart[tid] + fcpart[4+tid] + fcpart[8+tid] + fcpart[12+tid] + fcb[0];
}

extern "C" void kernel_launch(void* const* d_in, const int* in_sizes, int n_in,
                              void* d_out, int out_size, void* d_ws, size_t ws_size,
                              hipStream_t stream) {
  const float* x    = (const float*)d_in[0];
  const float* wih0 = (const float*)d_in[1];
  const float* whh0 = (const float*)d_in[2];
  const float* bih0 = (const float*)d_in[3];
  const float* bhh0 = (const float*)d_in[4];
  const float* wih1 = (const float*)d_in[5];
  const float* whh1 = (const float*)d_in[6];
  const float* bih1 = (const float*)d_in[7];
  const float* bhh1 = (const float*)d_in[8];
  const float* fcw  = (const float*)d_in[9];
  const float* fcb  = (const float*)d_in[10];
  float* out = (float*)d_out;

  hipLaunchKernelGGL(lstm_2wg, dim3(512), dim3(256), 0, stream,
                     x, wih0, whh0, bih0, bhh0, wih1, whh1, bih1, bhh1, fcw, fcb, out);
}

// Round 7
// 676.291 us; speedup vs baseline: 1.1151x; 1.1151x over previous
//
#include <hip/hip_runtime.h>

#define TSEQ 512

typedef _Float16 half8 __attribute__((ext_vector_type(8)));
typedef __attribute__((ext_vector_type(4))) float f32x4;

#define MFMAH(a,b,c) __builtin_amdgcn_mfma_f32_16x16x32_f16(a,b,c,0,0,0)

static __device__ __forceinline__ float sigm(float x){ return __builtin_amdgcn_rcpf(1.0f + __expf(-x)); }
static __device__ __forceinline__ float tanh_f(float x){ return 1.0f - 2.0f*__builtin_amdgcn_rcpf(__expf(2.0f*x)+1.0f); }

static __device__ __forceinline__ short f2h(float v){
  union { _Float16 h; short s; } u; u.h = (_Float16)v; return u.s;
}

// wait lgkmcnt(0) only (vmcnt left alone so x-prefetch stays in flight)
static __device__ __forceinline__ void lds_drain(){
  __builtin_amdgcn_s_waitcnt(0xC07F);
  __asm__ __volatile__("" ::: "memory");
}

// raw workgroup barrier WITHOUT the implicit vmcnt(0) drain of __syncthreads
static __device__ __forceinline__ void bar(){
  __asm__ __volatile__("" ::: "memory");
  __builtin_amdgcn_s_barrier();
  __asm__ __volatile__("" ::: "memory");
}

// DUAL-CHAIN LSTM (stall amortization INSIDE each wave).
// R0 (333us) is latency-bound: ~1190/1560 cyc/step are per-step FIXED
// stalls (gate-roundtrip lgkm wait, frag-read waits, barrier, trans
// latency). R1/R3/R6 tried to fill them with co-resident WGs and all
// died on the VGPR-spill cliff (weights don't fit 2 WGs' worth per CU).
// This version fills them with a SECOND independent recurrence chain in
// the SAME wave: 2 chains x 2 batch rows per WG (grid 256, 1 WG/CU).
//  - weights/bias SHARED between chains (same layer) -> no reg doubling
//  - both chains' MFMA streams + roundtrip writes issue before ONE
//    lgkmcnt(0); gate reads + trans interleave; ONE barrier/step
//  - stall count per step unchanged, work per stall doubled
// Regs ~175 (W64+Bq16+aF32+acc32+state) at (512,2) budget 256: no spill
// (tripwire: WRITE_SIZE must stay ~KB).
// Chain c owns batch rows b0+2c, b0+2c+1 (tile rows 2-15 garbage:
// clamped-x trajectory, row-isolated in matmul, sigmoid/tanh-bounded,
// never read for output). All index algebra (si/foff/roundtrip/cell
// mapping) is R0's harness-verified code, duplicated per chain.
// Wave wv: gm=wv>>2 (0: layer0 -> gates0(i+1); 1: layer1 -> gates1(i)),
// p=wv&3: col-quarter. act[c]: 0,1 x buf0/1; 2,3 h0; 4,5 h1.
extern "C" __global__ void __launch_bounds__(512, 2)
lstm_dual(const float* __restrict__ x,
          const float* __restrict__ wih0, const float* __restrict__ whh0,
          const float* __restrict__ bih0, const float* __restrict__ bhh0,
          const float* __restrict__ wih1, const float* __restrict__ whh1,
          const float* __restrict__ bih1, const float* __restrict__ bhh1,
          const float* __restrict__ fcw,  const float* __restrict__ fcb,
          float* __restrict__ out)
{
  __shared__ __align__(16) short act[2][6][256];      // [chain][buf][slot]
  __shared__ __align__(16) float gbuf[2][2][1024];    // [chain][gemm][q*256+jc*4+m]
  __shared__ float fcpart[2][16];

  const int tid = threadIdx.x;
  const int wv  = tid >> 6;
  const int gm  = wv >> 2;
  const int p   = wv & 3;
  const int ln  = tid & 63;
  const int lq  = ln >> 4;
  const int lr  = ln & 15;
  const int b0  = blockIdx.x << 2;               // 4 rows: chain0 = b0,b0+1; chain1 = b0+2,b0+3
  const int jc  = (p << 4) + lr;
  const int si  = (((jc>>5)*4 + ((jc>>3)&3))*4 + lq)*8 + (jc&7);
  const int foff = lq*32 + lr*8;
  const bool wlane = (lq == 0);

  // ---- one-time: fp16 weight B-frags [op][F][q] = 64 VGPR (shared by chains) ----
  half8 W[2][2][4];
  {
    const float* w_op[2] = { gm ? wih1 : wih0, gm ? whh1 : whh0 };
#pragma unroll
    for (int op = 0; op < 2; ++op)
#pragma unroll
      for (int F = 0; F < 2; ++F)
#pragma unroll
        for (int q = 0; q < 4; ++q){
          const float* src = w_op[op] + ((q<<6) + jc)*64 + F*32 + lq*8;
#pragma unroll
          for (int e = 0; e < 8; ++e)
            W[op][F][q][e] = (_Float16)src[e];
        }
  }
  // bias in MFMA C operand (shared by chains)
  f32x4 Bq[4];
  {
    const float* bi = gm ? bih1 : bih0;
    const float* bh = gm ? bhh1 : bhh0;
#pragma unroll
    for (int q = 0; q < 4; ++q){
      float b = bi[(q<<6)+jc] + bh[(q<<6)+jc];
      Bq[q][0] = b; Bq[q][1] = b; Bq[q][2] = b; Bq[q][3] = b;
    }
  }

  // x pointers per chain; tile rows lq>=2 are garbage -> clamp to chain row 0
  const int xr = (lq < 2) ? lq : 0;
  const float* xq0 = x + (size_t)(b0 + 0 + xr)*(TSEQ*64) + jc;
  const float* xq1 = x + (size_t)(b0 + 2 + xr)*(TSEQ*64) + jc;

  float cst[2]  = {0.f, 0.f};
  float hval[2] = {0.f, 0.f};
  float xv[2]   = {0.f, 0.f};
  half8 aF[2][4];   // persistent frags (masked loads leave lr>=4 lanes at zero: A rows 4-15 = 0)
#pragma unroll
  for (int c = 0; c < 2; ++c)
#pragma unroll
    for (int f = 0; f < 4; ++f) aF[c][f] = (half8){0,0,0,0,0,0,0,0};

  // ---- prologue: zero h1 bufs (act[c][4],act[c][5]) ----
  {
    const int c = tid >> 8, j = tid & 255;       // exactly 512 ints = 2 chains x 256
    ((int*)&act[c][4][0])[j] = 0;
  }
  if (gm == 0){
    act[0][0][si] = f2h(xq0[0]);   act[1][0][si] = f2h(xq1[0]);    // x(0)
    act[0][1][si] = f2h(xq0[64]);  act[1][1][si] = f2h(xq1[64]);   // x(1)
    xv[0] = xq0[128];              xv[1] = xq1[128];               // x(2)
  }
  __syncthreads();

  if (gm == 0){   // step 0: gates0(0) = x(0)·Wih0 + bias -> h0(0) buf0, both chains
    if (lr < 4){
      aF[0][0] = *(const half8*)(&act[0][0][0] + foff);
      aF[0][1] = *(const half8*)(&act[0][0][0] + foff + 128);
      aF[1][0] = *(const half8*)(&act[1][0][0] + foff);
      aF[1][1] = *(const half8*)(&act[1][0][0] + foff + 128);
    }
    f32x4 acc[2][4];
#pragma unroll
    for (int c = 0; c < 2; ++c)
#pragma unroll
      for (int q = 0; q < 4; ++q){
        acc[c][q] = MFMAH(aF[c][0], W[0][0][q], Bq[q]);
        acc[c][q] = MFMAH(aF[c][1], W[0][1][q], acc[c][q]);
      }
    if (wlane){
#pragma unroll
      for (int c = 0; c < 2; ++c)
#pragma unroll
        for (int q = 0; q < 4; ++q) *(f32x4*)&gbuf[c][0][q*256 + jc*4] = acc[c][q];
    }
    lds_drain();
#pragma unroll
    for (int c = 0; c < 2; ++c){
      float gi = sigm  (gbuf[c][0][0*256 + jc*4 + lq]);
      float gf = sigm  (gbuf[c][0][1*256 + jc*4 + lq]);
      float gg = tanh_f(gbuf[c][0][2*256 + jc*4 + lq]);
      float go = sigm  (gbuf[c][0][3*256 + jc*4 + lq]);
      cst[c]  = gf*cst[c] + gi*gg;
      hval[c] = go * tanh_f(cst[c]);
      act[c][2][si] = f2h(hval[c]);
    }
  }
  __syncthreads();

  // ---- main loops: divergent by gemm, ONE raw barrier per iteration ----
  if (gm == 1){
#pragma unroll 2
    for (int i = 0; i < TSEQ; ++i){
      const int cb = i & 1, nb = cb ^ 1;
      // gates1(i) = h0(i)·Wih1 + h1(i-1)·Whh1 + bias, both chains
      if (lr < 4){
        aF[0][0] = *(const half8*)(&act[0][2+cb][0] + foff);
        aF[0][1] = *(const half8*)(&act[0][2+cb][0] + foff + 128);
        aF[0][2] = *(const half8*)(&act[0][4+nb][0] + foff);
        aF[0][3] = *(const half8*)(&act[0][4+nb][0] + foff + 128);
        aF[1][0] = *(const half8*)(&act[1][2+cb][0] + foff);
        aF[1][1] = *(const half8*)(&act[1][2+cb][0] + foff + 128);
        aF[1][2] = *(const half8*)(&act[1][4+nb][0] + foff);
        aF[1][3] = *(const half8*)(&act[1][4+nb][0] + foff + 128);
      }
      f32x4 acc[2][4];
#pragma unroll
      for (int c = 0; c < 2; ++c)
#pragma unroll
        for (int q = 0; q < 4; ++q){
          acc[c][q] = MFMAH(aF[c][0], W[0][0][q], Bq[q]);
          acc[c][q] = MFMAH(aF[c][1], W[0][1][q], acc[c][q]);
          acc[c][q] = MFMAH(aF[c][2], W[1][0][q], acc[c][q]);
          acc[c][q] = MFMAH(aF[c][3], W[1][1][q], acc[c][q]);
        }
      if (wlane){
#pragma unroll
        for (int c = 0; c < 2; ++c)
#pragma unroll
          for (int q = 0; q < 4; ++q) *(f32x4*)&gbuf[c][1][q*256 + jc*4] = acc[c][q];
      }
      lds_drain();
#pragma unroll
      for (int c = 0; c < 2; ++c){
        float gi = sigm  (gbuf[c][1][0*256 + jc*4 + lq]);
        float gf = sigm  (gbuf[c][1][1*256 + jc*4 + lq]);
        float gg = tanh_f(gbuf[c][1][2*256 + jc*4 + lq]);
        float go = sigm  (gbuf[c][1][3*256 + jc*4 + lq]);
        cst[c]  = gf*cst[c] + gi*gg;
        hval[c] = go * tanh_f(cst[c]);
        act[c][4+cb][si] = f2h(hval[c]);   // h1(i)
      }
      lds_drain();
      bar();
    }
  } else {
#pragma unroll 2
    for (int i = 0; i < TSEQ; ++i){
      const int cb = i & 1, nb = cb ^ 1;
      if (i < TSEQ-1){
        // gates0(i+1) = x(i+1)·Wih0 + h0(i)·Whh0 + bias, both chains
        if (lr < 4){
          aF[0][0] = *(const half8*)(&act[0][0+nb][0] + foff);
          aF[0][1] = *(const half8*)(&act[0][0+nb][0] + foff + 128);
          aF[0][2] = *(const half8*)(&act[0][2+cb][0] + foff);
          aF[0][3] = *(const half8*)(&act[0][2+cb][0] + foff + 128);
          aF[1][0] = *(const half8*)(&act[1][0+nb][0] + foff);
          aF[1][1] = *(const half8*)(&act[1][0+nb][0] + foff + 128);
          aF[1][2] = *(const half8*)(&act[1][2+cb][0] + foff);
          aF[1][3] = *(const half8*)(&act[1][2+cb][0] + foff + 128);
        }
        f32x4 acc[2][4];
#pragma unroll
        for (int c = 0; c < 2; ++c)
#pragma unroll
          for (int q = 0; q < 4; ++q){
            acc[c][q] = MFMAH(aF[c][0], W[0][0][q], Bq[q]);
            acc[c][q] = MFMAH(aF[c][1], W[0][1][q], acc[c][q]);
            acc[c][q] = MFMAH(aF[c][2], W[1][0][q], acc[c][q]);
            acc[c][q] = MFMAH(aF[c][3], W[1][1][q], acc[c][q]);
          }
        if (wlane){
#pragma unroll
          for (int c = 0; c < 2; ++c)
#pragma unroll
            for (int q = 0; q < 4; ++q) *(f32x4*)&gbuf[c][0][q*256 + jc*4] = acc[c][q];
        }
        lds_drain();
#pragma unroll
        for (int c = 0; c < 2; ++c){
          float gi = sigm  (gbuf[c][0][0*256 + jc*4 + lq]);
          float gf = sigm  (gbuf[c][0][1*256 + jc*4 + lq]);
          float gg = tanh_f(gbuf[c][0][2*256 + jc*4 + lq]);
          float go = sigm  (gbuf[c][0][3*256 + jc*4 + lq]);
          cst[c]  = gf*cst[c] + gi*gg;
          hval[c] = go * tanh_f(cst[c]);
          act[c][2+nb][si] = f2h(hval[c]);   // h0(i+1)
        }
        if (i < TSEQ-2){
          act[0][0+cb][si] = f2h(xv[0]);     // stage x(i+2)
          act[1][0+cb][si] = f2h(xv[1]);
        }
        int tn = i + 3; if (tn > TSEQ-1) tn = TSEQ-1;
        xv[0] = xq0[tn << 6];                // prefetch x(i+3)
        xv[1] = xq1[tn << 6];
      }
      lds_drain();
      bar();
    }
  }

  // ---- FC head: gm1 waves hold h1(T-1) for (m=lq, j=jc), per chain ----
  if (gm == 1){
#pragma unroll
    for (int c = 0; c < 2; ++c){
      float v = hval[c] * fcw[jc];
      v += __shfl_xor(v, 1); v += __shfl_xor(v, 2);
      v += __shfl_xor(v, 4); v += __shfl_xor(v, 8);
      if (lr == 0) fcpart[c][p*4 + lq] = v;
    }
  }
  __syncthreads();
  if (tid < 4){
    const int c = tid >> 1, r = tid & 1;     // chain, row-within-chain
    out[b0 + c*2 + r] = fcpart[c][r] + fcpart[c][4+r] + fcpart[c][8+r] + fcpart[c][12+r] + fcb[0];
  }
}

extern "C" void kernel_launch(void* const* d_in, const int* in_sizes, int n_in,
                              void* d_out, int out_size, void* d_ws, size_t ws_size,
                              hipStream_t stream) {
  const float* x    = (const float*)d_in[0];
  const float* wih0 = (const float*)d_in[1];
  const float* whh0 = (const float*)d_in[2];
  const float* bih0 = (const float*)d_in[3];
  const float* bhh0 = (const float*)d_in[4];
  const float* wih1 = (const float*)d_in[5];
  const float* whh1 = (const float*)d_in[6];
  const float* bih1 = (const float*)d_in[7];
  const float* bhh1 = (const float*)d_in[8];
  const float* fcw  = (const float*)d_in[9];
  const float* fcb  = (const float*)d_in[10];
  float* out = (float*)d_out;

  hipLaunchKernelGGL(lstm_dual, dim3(256), dim3(512), 0, stream,
                     x, wih0, whh0, bih0, bhh0, wih1, whh1, bih1, bhh1, fcw, fcb, out);
}

// Round 9
// 488.538 us; speedup vs baseline: 1.5437x; 1.3843x over previous
//
#include <hip/hip_runtime.h>

#define TSEQ 512

typedef _Float16 half8 __attribute__((ext_vector_type(8)));
typedef __attribute__((ext_vector_type(4))) float f32x4;

#define MFMAH(a,b,c) __builtin_amdgcn_mfma_f32_16x16x32_f16(a,b,c,0,0,0)

static __device__ __forceinline__ float sigm(float x){ return __builtin_amdgcn_rcpf(1.0f + __expf(-x)); }
static __device__ __forceinline__ float tanh_f(float x){ return 1.0f - 2.0f*__builtin_amdgcn_rcpf(__expf(2.0f*x)+1.0f); }

static __device__ __forceinline__ short f2h(float v){
  union { _Float16 h; short s; } u; u.h = (_Float16)v; return u.s;
}

// wait lgkmcnt(0) only (vmcnt left alone so x-prefetch stays in flight)
static __device__ __forceinline__ void lds_drain(){
  __builtin_amdgcn_s_waitcnt(0xC07F);
  __asm__ __volatile__("" ::: "memory");
}

// raw workgroup barrier WITHOUT the implicit vmcnt(0) drain of __syncthreads
static __device__ __forceinline__ void bar(){
  __asm__ __volatile__("" ::: "memory");
  __builtin_amdgcn_s_barrier();
  __asm__ __volatile__("" ::: "memory");
}

// 16-WAVE SPLIT-WEIGHT LSTM (R8 resubmit; infra failed, no signal).
// R7 proved the kernel is per-wave issue-throughput-bound (2x in-wave
// work -> 1.8x time); only more waves/SIMD helps, and 2-WG co-residency
// died 3x on the VGPR cliff (8-wave WG = 64 weight-VGPR/thread). Fix:
// ONE 16-wave WG (1024 thr, 4 waves/SIMD, grid 256 = 1 WG/CU) with
// weights spread over 2x waves.
// Per gemm: 8 waves = 4 col-quarters (p) x 2 gate-pairs (s: q={2s,2s+1}).
// Each wave: 32 weight VGPRs, 8 MFMA/step (complete gates for its
// q-pair, both operands -> NO partial sums). Total live ~85 <= 128
// budget at (1024,4). Cost: gates cross waves -> TWO barriers/step
// (MFMA-phase bar, cell-phase bar).
// Cell/h-write/x-staging on waves sub in {0,3,5,6} (even parity): one
// per SIMD -> balanced transcendental load; their p covers 0..3.
// All index algebra (si frag staging, foff A-frag reads, gbuf
// [q*256+jc*4+m] layout, cell mapping, gm0-one-step-ahead pipeline)
// is R0's harness-verified code.
// R8 fix: A-frag reads CLAMPED (foffc uses lr&3) so lanes lr>=4 re-read
// rows 0-3's addresses -- always in-bounds (max short idx 255 < 256);
// their D-rows 4-15 are duplicates, never read. (Unmasked version read
// ~95 shorts past act[5] into gbuf: in-LDS but OOB-by-construction.)
// act arrs: 0,1 x buf0/1; 2,3 h0 buf0/1; 4,5 h1 buf0/1.
// Tripwire: VGPR_Count==64 + WRITE_SIZE in MBs = allocator split
// heuristic spilled -> abandon this axis.
extern "C" __global__ void __launch_bounds__(1024, 4)
lstm_16w(const float* __restrict__ x,
         const float* __restrict__ wih0, const float* __restrict__ whh0,
         const float* __restrict__ bih0, const float* __restrict__ bhh0,
         const float* __restrict__ wih1, const float* __restrict__ whh1,
         const float* __restrict__ bih1, const float* __restrict__ bhh1,
         const float* __restrict__ fcw,  const float* __restrict__ fcb,
         float* __restrict__ out)
{
  __shared__ __align__(16) short act[6][256];
  __shared__ __align__(16) float gbuf[2][1024];   // [gemm][q*256 + jc*4 + m]
  __shared__ float fcpart[16];

  const int tid = threadIdx.x;                   // 0..1023
  const int wv  = tid >> 6;                      // 0..15
  const int gm  = wv >> 3;                       // gemm (0: layer0, 1: layer1)
  const int sub = wv & 7;
  const int p   = sub >> 1;                      // col-quarter
  const int s   = sub & 1;                       // gate-pair: q in {2s, 2s+1}
  const bool cellw = (((sub ^ (sub>>1) ^ (sub>>2)) & 1) == 0);  // {0,3,5,6}: one per SIMD
  const int ln  = tid & 63;
  const int lq  = ln >> 4;
  const int lr  = ln & 15;
  const int b0  = blockIdx.x << 2;               // 4 batch rows per WG
  const int jc  = (p << 4) + lr;                 // gemm col / cell col
  const int si  = (((jc>>5)*4 + ((jc>>3)&3))*4 + lq)*8 + (jc&7);
  const int foffc = lq*32 + (lr&3)*8;            // CLAMPED A-frag read offset (in-bounds all lanes)
  float* const gme = &gbuf[gm][0];
  const bool wlane = (lq == 0);

  // ---- one-time: fp16 weight B-frags [op][F][jq] = 32 VGPR (q = 2s+jq) ----
  half8 W[2][2][2];
  {
    const float* w_op[2] = { gm ? wih1 : wih0, gm ? whh1 : whh0 };
#pragma unroll
    for (int op = 0; op < 2; ++op)
#pragma unroll
      for (int F = 0; F < 2; ++F)
#pragma unroll
        for (int jq = 0; jq < 2; ++jq){
          const float* src = w_op[op] + (((((s<<1)+jq)<<6) + jc)*64) + F*32 + lq*8;
#pragma unroll
          for (int e = 0; e < 8; ++e)
            W[op][F][jq][e] = (_Float16)src[e];
        }
  }
  // bias as scalars for cell threads (applied post-roundtrip)
  float bq0, bq1, bq2, bq3;
  {
    const float* bi = gm ? bih1 : bih0;
    const float* bh = gm ? bhh1 : bhh0;
    bq0 = bi[0*64+jc] + bh[0*64+jc];
    bq1 = bi[1*64+jc] + bh[1*64+jc];
    bq2 = bi[2*64+jc] + bh[2*64+jc];
    bq3 = bi[3*64+jc] + bh[3*64+jc];
  }
  const f32x4 Zq = {0.f, 0.f, 0.f, 0.f};

  const float* xq = x + (size_t)(b0 + lq)*(TSEQ*64) + jc;   // lq 0..3 all real

  float cst = 0.f, hval = 0.f, xv = 0.f;

  // ---- prologue: zero h bufs, stage x(0),x(1), prefetch x(2) ----
  if (tid < 512) ((int*)&act[2][0])[tid] = 0;    // act[2..5] = 512 ints
  if (gm == 0 && cellw){
    act[0][si] = f2h(xq[0]);
    act[1][si] = f2h(xq[64]);
    xv = xq[128];
  }
  __syncthreads();

  // step 0: gates0(0) = x(0)·Wih0 + bias (h0(-1)=0) -> h0(0) buf0
  {
    if (gm == 0){
      half8 a0 = *(const half8*)(&act[0][0] + foffc);
      half8 a1 = *(const half8*)(&act[0][0] + foffc + 128);
      f32x4 acc[2];
#pragma unroll
      for (int jq = 0; jq < 2; ++jq){
        acc[jq] = MFMAH(a0, W[0][0][jq], Zq);
        acc[jq] = MFMAH(a1, W[0][1][jq], acc[jq]);
      }
      if (wlane){
        *(f32x4*)&gme[((s<<1)+0)*256 + jc*4] = acc[0];
        *(f32x4*)&gme[((s<<1)+1)*256 + jc*4] = acc[1];
      }
      lds_drain();
    }
    bar();
    if (gm == 0 && cellw){
      float gi = sigm  (gme[0*256 + jc*4 + lq] + bq0);
      float gf = sigm  (gme[1*256 + jc*4 + lq] + bq1);
      float gg = tanh_f(gme[2*256 + jc*4 + lq] + bq2);
      float go = sigm  (gme[3*256 + jc*4 + lq] + bq3);
      cst  = gf*cst + gi*gg;
      hval = go * tanh_f(cst);
      act[2][si] = f2h(hval);
    }
    lds_drain();
    bar();
  }

  // ---- main loops: divergent by gemm, TWO raw barriers per iteration ----
  if (gm == 1){
#pragma unroll 2
    for (int i = 0; i < TSEQ; ++i){
      const int cb = i & 1, nb = cb ^ 1;
      // gates1(i) = h0(i)·Wih1 + h1(i-1)·Whh1 + bias
      {
        half8 a0 = *(const half8*)(&act[2+cb][0] + foffc);
        half8 a1 = *(const half8*)(&act[2+cb][0] + foffc + 128);
        half8 b0v = *(const half8*)(&act[4+nb][0] + foffc);
        half8 b1v = *(const half8*)(&act[4+nb][0] + foffc + 128);
        f32x4 acc[2];
#pragma unroll
        for (int jq = 0; jq < 2; ++jq){
          acc[jq] = MFMAH(a0,  W[0][0][jq], Zq);
          acc[jq] = MFMAH(b0v, W[1][0][jq], acc[jq]);
          acc[jq] = MFMAH(a1,  W[0][1][jq], acc[jq]);
          acc[jq] = MFMAH(b1v, W[1][1][jq], acc[jq]);
        }
        if (wlane){
          *(f32x4*)&gme[((s<<1)+0)*256 + jc*4] = acc[0];
          *(f32x4*)&gme[((s<<1)+1)*256 + jc*4] = acc[1];
        }
      }
      lds_drain();
      bar();
      if (cellw){
        float gi = sigm  (gme[0*256 + jc*4 + lq] + bq0);
        float gf = sigm  (gme[1*256 + jc*4 + lq] + bq1);
        float gg = tanh_f(gme[2*256 + jc*4 + lq] + bq2);
        float go = sigm  (gme[3*256 + jc*4 + lq] + bq3);
        cst  = gf*cst + gi*gg;
        hval = go * tanh_f(cst);
        act[4+cb][si] = f2h(hval);               // h1(i)
      }
      lds_drain();
      bar();
    }
  } else {
#pragma unroll 2
    for (int i = 0; i < TSEQ; ++i){
      const int cb = i & 1, nb = cb ^ 1;
      if (i < TSEQ-1){
        // gates0(i+1) = x(i+1)·Wih0 + h0(i)·Whh0 + bias
        half8 a0 = *(const half8*)(&act[0+nb][0] + foffc);
        half8 a1 = *(const half8*)(&act[0+nb][0] + foffc + 128);
        half8 b0v = *(const half8*)(&act[2+cb][0] + foffc);
        half8 b1v = *(const half8*)(&act[2+cb][0] + foffc + 128);
        f32x4 acc[2];
#pragma unroll
        for (int jq = 0; jq < 2; ++jq){
          acc[jq] = MFMAH(a0,  W[0][0][jq], Zq);
          acc[jq] = MFMAH(b0v, W[1][0][jq], acc[jq]);
          acc[jq] = MFMAH(a1,  W[0][1][jq], acc[jq]);
          acc[jq] = MFMAH(b1v, W[1][1][jq], acc[jq]);
        }
        if (wlane){
          *(f32x4*)&gme[((s<<1)+0)*256 + jc*4] = acc[0];
          *(f32x4*)&gme[((s<<1)+1)*256 + jc*4] = acc[1];
        }
        lds_drain();
      }
      bar();
      if (i < TSEQ-1 && cellw){
        float gi = sigm  (gme[0*256 + jc*4 + lq] + bq0);
        float gf = sigm  (gme[1*256 + jc*4 + lq] + bq1);
        float gg = tanh_f(gme[2*256 + jc*4 + lq] + bq2);
        float go = sigm  (gme[3*256 + jc*4 + lq] + bq3);
        cst  = gf*cst + gi*gg;
        hval = go * tanh_f(cst);
        act[2+nb][si] = f2h(hval);               // h0(i+1)
        if (i < TSEQ-2) act[0+cb][si] = f2h(xv); // stage x(i+2)
        int tn = i + 3; if (tn > TSEQ-1) tn = TSEQ-1;
        xv = xq[tn << 6];                        // prefetch x(i+3)
      }
      lds_drain();
      bar();
    }
  }

  // ---- FC head: gm1 cell waves hold h1(T-1) for (m=lq, j=jc) ----
  if (gm == 1 && cellw){
    float v = hval * fcw[jc];
    v += __shfl_xor(v, 1); v += __shfl_xor(v, 2);
    v += __shfl_xor(v, 4); v += __shfl_xor(v, 8);
    if (lr == 0) fcpart[p*4 + lq] = v;
  }
  __syncthreads();
  if (tid < 4)
    out[b0 + tid] = fcpart[tid] + fcpart[4+tid] + fcpart[8+tid] + fcpart[12+tid] + fcb[0];
}

extern "C" void kernel_launch(void* const* d_in, const int* in_sizes, int n_in,
                              void* d_out, int out_size, void* d_ws, size_t ws_size,
                              hipStream_t stream) {
  const float* x    = (const float*)d_in[0];
  const float* wih0 = (const float*)d_in[1];
  const float* whh0 = (const float*)d_in[2];
  const float* bih0 = (const float*)d_in[3];
  const float* bhh0 = (const float*)d_in[4];
  const float* wih1 = (const float*)d_in[5];
  const float* whh1 = (const float*)d_in[6];
  const float* bih1 = (const float*)d_in[7];
  const float* bhh1 = (const float*)d_in[8];
  const float* fcw  = (const float*)d_in[9];
  const float* fcb  = (const float*)d_in[10];
  float* out = (float*)d_out;

  hipLaunchKernelGGL(lstm_16w, dim3(256), dim3(1024), 0, stream,
                     x, wih0, whh0, bih0, bhh0, wih1, whh1, bih1, bhh1, fcw, fcb, out);
}